// Round 22
// baseline (12622.388 us; speedup 1.0000x reference)
//
#include <hip/hip_runtime.h>
#include <math.h>

#define BB 32
#define TT 2048
#define FF 16
#define CC 17
#define HH 64

typedef float v2f __attribute__((ext_vector_type(2)));
typedef float v4f __attribute__((ext_vector_type(4)));
typedef unsigned v4u __attribute__((ext_vector_type(4)));
typedef _Float16 h2 __attribute__((ext_vector_type(2)));

__device__ __forceinline__ float rl(float v, int lane) {
    return __int_as_float(__builtin_amdgcn_readlane(__float_as_int(v), lane));
}
__device__ __forceinline__ unsigned rlu(unsigned v, int lane) {
    return (unsigned)__builtin_amdgcn_readlane((int)v, lane);
}
__device__ __forceinline__ float uf(float v) {
    return __int_as_float(__builtin_amdgcn_readfirstlane(__float_as_int(v)));
}
__device__ __forceinline__ float ftanh(float x) {
    float e = __builtin_amdgcn_exp2f(x * 2.88539008177792681472f); // exp(2x)
    return 1.0f - 2.0f * __builtin_amdgcn_rcpf(e + 1.0f);
}
__device__ __forceinline__ float fdot2u(unsigned a, unsigned b, float c) {
    return __builtin_amdgcn_fdot2(__builtin_bit_cast(h2, a),
                                  __builtin_bit_cast(h2, b), c, false);
}
// pack (a,b) to f16x2, scaled by 2^8 (weights); RN; init-time only
__device__ __forceinline__ unsigned packw(float a, float b) {
    h2 p; p.x = (_Float16)(a * 256.0f); p.y = (_Float16)(b * 256.0f);
    return __builtin_bit_cast(unsigned, p);
}
// LDS-only barrier: no vmcnt(0) drain.
__device__ __forceinline__ void bar_lds() {
    asm volatile("s_waitcnt lgkmcnt(0)\n\ts_barrier" ::: "memory");
}
#define PIN(v)  asm volatile("" : "+v"(v))
#define PINA(v) asm volatile("" : "+a"(v))

// R22: single-wave hidden chain, TWO barriers/G (was 3 in R20/R21, 5 in R14).
//  wave 0: ALL 4 hidden layers in-register -- L0/L1 weights in VGPRs,
//          L2/L3 weights AGPR-pinned ("+a"; accvgpr_read per use ~2cy beats
//          the removed barrier-A + w1 LDS-read round ~400-500cy).
//  waves 1-7: out layer, {3,3,3,2,2,2,2} columns; pg combine = 7 permuted
//          slots + zeroed 8th column (2 x b128 reads).
// Lineage: R14 5-round=12.6ms -> R20 3-round=11.72 -> this 2-round.
__attribute__((amdgpu_waves_per_eu(2, 2)))
__launch_bounds__(512)
__global__ void ncde_main(const float* __restrict__ x,
                          const float* __restrict__ wi1, const float* __restrict__ bi1,
                          const float* __restrict__ wi2, const float* __restrict__ bi2,
                          const float* __restrict__ w_in, const float* __restrict__ b_in,
                          const float* __restrict__ w_hid, const float* __restrict__ b_hid,
                          const float* __restrict__ w_out, const float* __restrict__ b_out,
                          float* __restrict__ zT)
{
    const int b   = blockIdx.x;
    const int tid = threadIdx.x;
    const int w   = tid >> 6;
    const int l   = tid & 63;

    __shared__ __align__(16) unsigned hbuf[32];  // h4 (w0 -> out waves)
    __shared__ float pgqt[64][20];               // [h-row][7 pg cols + zero col + pad]

    // role parameters (wave-uniform)
    const int nc    = (w == 0) ? 0 : ((w <= 3) ? 3 : 2);        // out columns owned
    const int cbase = (w == 0) ? 0 : ((w <= 3) ? 3 * (w - 1) : 9 + 2 * (w - 4));
    const int pcol  = (w >= 1) ? ((w - 1 + (l >> 3)) % 7) : 0;  // permuted pg slot

    // ---- weights ----
    unsigned wregV[96];   // w0: L0,L1 in [0..63]; out waves: up to 3 columns
    unsigned wregA[64];   // w0 only: L2,L3 (AGPR-pinned)
    #pragma unroll
    for (int i = 0; i < 96; ++i) wregV[i] = 0u;
    #pragma unroll
    for (int i = 0; i < 64; ++i) wregA[i] = 0u;
    float bA = 0.f, bB = 0.f, bC = 0.f, bD = 0.f;
    if (w == 0) {
        #pragma unroll
        for (int p = 0; p < 32; ++p) {
            wregV[p]      = packw(w_in[(2 * p) * HH + l],           w_in[(2 * p + 1) * HH + l]);
            wregV[32 + p] = packw(w_hid[(0 * HH + 2 * p) * HH + l],  w_hid[(0 * HH + 2 * p + 1) * HH + l]);
            wregA[p]      = packw(w_hid[(1 * HH + 2 * p) * HH + l],  w_hid[(1 * HH + 2 * p + 1) * HH + l]);
            wregA[32 + p] = packw(w_hid[(2 * HH + 2 * p) * HH + l],  w_hid[(2 * HH + 2 * p + 1) * HH + l]);
        }
        bA = b_in[l];           // L0 bias
        bB = b_hid[l];          // L1 bias
        bC = b_hid[HH + l];     // L2 bias
        bD = b_hid[2 * HH + l]; // L3 bias
    } else {
        #pragma unroll
        for (int i = 0; i < 3; ++i) {
            if (i < nc) {
                int c = cbase + i;
                #pragma unroll
                for (int p = 0; p < 32; ++p)
                    wregV[32 * i + p] = packw(w_out[(2 * p) * (CC * HH) + l * CC + c],
                                              w_out[(2 * p + 1) * (CC * HH) + l * CC + c]);
            }
        }
        bA = b_out[l * CC + cbase];
        bB = b_out[l * CC + cbase + 1];
        if (nc == 3) bC = b_out[l * CC + cbase + 2];
    }
    #pragma unroll
    for (int i = 0; i < 96; ++i) PIN(wregV[i]);
    #pragma unroll
    for (int i = 0; i < 64; ++i) PINA(wregA[i]);
    PIN(bA); PIN(bB); PIN(bC); PIN(bD);

    // zero the unused 8th combine column (cols 0..6 rewritten each G; col 7
    // stays 0 forever; visibility ordered by the first G's barrier C)
    if (w == 0) pgqt[l][7] = 0.0f;

    // ---- z0 = relu(xa0 @ wi1 + bi1) @ wi2 + bi2 (f32, once, all waves) ----
    float z;
    {
        float h0 = bi1[l];
        #pragma unroll
        for (int c = 1; c < CC; ++c)
            h0 = fmaf(x[(size_t)b * TT * FF + (c - 1)], wi1[c * HH + l], h0);
        h0 = fmaxf(h0, 0.0f);
        z = bi2[l];
        #pragma unroll
        for (int k = 0; k < 64; ++k)
            z = fmaf(rl(h0, k), wi2[k * HH + l], z);
    }
    if (w == 7) zT[(size_t)b * TT * HH + l] = z;

    // pack v*2^-8 into f16x2; every lane ends holding pair (v[2j],v[2j+1]), j=l>>1
    auto packb = [&](float v) -> unsigned {
        float hs = v * 0.00390625f;
        float pr = __shfl_xor(hs, 1);
        float a  = (l & 1) ? pr : hs;
        float bb = (l & 1) ? hs : pr;
        return __builtin_bit_cast(unsigned, __builtin_amdgcn_cvt_pkrtz(a, bb));
    };

    // full 64-wide matvec column for lane l; h pairs broadcast via readlane
    auto LAYER_RL = [&](const unsigned* Wc, float bias, unsigned hp) -> float {
        float a0 = bias, a1 = 0.f, a2 = 0.f, a3 = 0.f;
        #pragma unroll
        for (int p = 0; p < 32; p += 4) {
            unsigned s0 = rlu(hp, 2 * p);
            unsigned s1 = rlu(hp, 2 * p + 2);
            unsigned s2 = rlu(hp, 2 * p + 4);
            unsigned s3 = rlu(hp, 2 * p + 6);
            a0 = fdot2u(s0, Wc[p],     a0);
            a1 = fdot2u(s1, Wc[p + 1], a1);
            a2 = fdot2u(s2, Wc[p + 2], a2);
            a3 = fdot2u(s3, Wc[p + 3], a3);
        }
        return fmaxf((a0 + a1) + (a2 + a3), 0.0f);
    };
    // out-layer dot from preloaded q regs (no relu)
    auto DOT32 = [&](const unsigned* Wc, float bias,
                     v4u q0, v4u q1, v4u q2, v4u q3,
                     v4u q4, v4u q5, v4u q6, v4u q7) -> float {
        float a0 = bias, a1 = 0.f, a2 = 0.f, a3 = 0.f;
        a0 = fdot2u(q0.x, Wc[0],  a0); a1 = fdot2u(q0.y, Wc[1],  a1);
        a2 = fdot2u(q0.z, Wc[2],  a2); a3 = fdot2u(q0.w, Wc[3],  a3);
        a0 = fdot2u(q1.x, Wc[4],  a0); a1 = fdot2u(q1.y, Wc[5],  a1);
        a2 = fdot2u(q1.z, Wc[6],  a2); a3 = fdot2u(q1.w, Wc[7],  a3);
        a0 = fdot2u(q2.x, Wc[8],  a0); a1 = fdot2u(q2.y, Wc[9],  a1);
        a2 = fdot2u(q2.z, Wc[10], a2); a3 = fdot2u(q2.w, Wc[11], a3);
        a0 = fdot2u(q3.x, Wc[12], a0); a1 = fdot2u(q3.y, Wc[13], a1);
        a2 = fdot2u(q3.z, Wc[14], a2); a3 = fdot2u(q3.w, Wc[15], a3);
        a0 = fdot2u(q4.x, Wc[16], a0); a1 = fdot2u(q4.y, Wc[17], a1);
        a2 = fdot2u(q4.z, Wc[18], a2); a3 = fdot2u(q4.w, Wc[19], a3);
        a0 = fdot2u(q5.x, Wc[20], a0); a1 = fdot2u(q5.y, Wc[21], a1);
        a2 = fdot2u(q5.z, Wc[22], a2); a3 = fdot2u(q5.w, Wc[23], a3);
        a0 = fdot2u(q6.x, Wc[24], a0); a1 = fdot2u(q6.y, Wc[25], a1);
        a2 = fdot2u(q6.z, Wc[26], a2); a3 = fdot2u(q6.w, Wc[27], a3);
        a0 = fdot2u(q7.x, Wc[28], a0); a1 = fdot2u(q7.y, Wc[29], a1);
        a2 = fdot2u(q7.z, Wc[30], a2); a3 = fdot2u(q7.w, Wc[31], a3);
        return (a0 + a1) + (a2 + a3);
    };

    // ---- g(zin, xd[3]) : 2-barrier pipeline ----
    auto G = [&](float zin, float xd0, float xd1, float xd2) -> float {
        if (w == 0) {
            unsigned hp = packb(zin);
            hp = packb(LAYER_RL(&wregV[0],  bA, hp));   // L0 (VGPR weights)
            hp = packb(LAYER_RL(&wregV[32], bB, hp));   // L1
            hp = packb(LAYER_RL(&wregA[0],  bC, hp));   // L2 (AGPR weights)
            hp = packb(LAYER_RL(&wregA[32], bD, hp));   // L3
            if (!(l & 1)) hbuf[l >> 1] = hp;
        }
        bar_lds();   // B: h4 published
        if (w >= 1) {
            v4u q0 = *reinterpret_cast<const v4u*>(&hbuf[0]);
            v4u q1 = *reinterpret_cast<const v4u*>(&hbuf[4]);
            v4u q2 = *reinterpret_cast<const v4u*>(&hbuf[8]);
            v4u q3 = *reinterpret_cast<const v4u*>(&hbuf[12]);
            v4u q4 = *reinterpret_cast<const v4u*>(&hbuf[16]);
            v4u q5 = *reinterpret_cast<const v4u*>(&hbuf[20]);
            v4u q6 = *reinterpret_cast<const v4u*>(&hbuf[24]);
            v4u q7 = *reinterpret_cast<const v4u*>(&hbuf[28]);
            float u0 = DOT32(&wregV[0],  bA, q0, q1, q2, q3, q4, q5, q6, q7);
            float u1 = DOT32(&wregV[32], bB, q0, q1, q2, q3, q4, q5, q6, q7);
            float pg = ftanh(u0) * xd0 + ftanh(u1) * xd1;
            if (nc == 3) {
                float u2 = DOT32(&wregV[64], bC, q0, q1, q2, q3, q4, q5, q6, q7);
                pg = fmaf(ftanh(u2), xd2, pg);
            }
            pgqt[l][pcol] = pg;    // permuted slot: bijective per row
        }
        bar_lds();   // C: pg partials published
        const float* pr = &pgqt[l][0];
        v4f r0 = *reinterpret_cast<const v4f*>(pr);
        v4f r1 = *reinterpret_cast<const v4f*>(pr + 4);   // col 7 is always 0
        return ((r0.x + r0.y) + (r0.z + r0.w)) + ((r1.x + r1.y) + (r1.z + r1.w));
    };

    // ---- time scan: wave w carries xd for its out columns (nc of them) ----
    const float* xb = x + (size_t)b * TT * FF;
    float xp[3] = {0, 0, 0}, dcv[3] = {0, 0, 0}, dpv[3] = {0, 0, 0};
    #pragma unroll
    for (int i = 0; i < 3; ++i) {
        if (i < nc) {
            int f = cbase + i - 1;              // feature; f<0 => time channel
            float v0 = (f < 0) ? 0.f : uf(xb[f]);
            float v1 = (f < 0) ? 0.f : uf(xb[FF + f]);
            dcv[i] = (f < 0) ? 1.0f : (v1 - v0);
            dpv[i] = dcv[i];
            xp[i]  = v1;
        }
    }

    #pragma unroll 1
    for (int t = 0; t < TT - 1; ++t) {
        const float f43 = 4.0f / 3.0f;
        float x2[3] = {0, 0, 0};
        #pragma unroll
        for (int i = 0; i < 3; ++i)
            if (i < nc) x2[i] = dpv[i] + f43 * (dcv[i] - dpv[i]);

        int tn = (t + 2 < TT) ? (t + 2) : (TT - 1);
        float yn[3] = {0, 0, 0};
        #pragma unroll
        for (int i = 0; i < 3; ++i) {
            if (i < nc) {
                int f = cbase + i - 1;
                yn[i] = (f < 0) ? 0.f : uf(xb[tn * FF + f]);
            }
        }

        float k1 = G(z, dpv[0], dpv[1], dpv[2]);
        float k2 = G(z + k1 * (1.0f / 3.0f), dcv[0], dcv[1], dcv[2]);
        float k3 = G(z + (k2 - k1 * (1.0f / 3.0f)), x2[0], x2[1], x2[2]);
        float k4 = G(z + (k1 - k2 + k3), dcv[0], dcv[1], dcv[2]);
        z = z + 0.125f * (k1 + 3.0f * (k2 + k3) + k4);

        if (w == 7) zT[((size_t)b * TT + t + 1) * HH + l] = z;

        #pragma unroll
        for (int i = 0; i < 3; ++i) {
            if (i < nc) {
                int f = cbase + i - 1;
                dpv[i] = dcv[i];
                dcv[i] = (f < 0) ? 1.0f : (yn[i] - xp[i]);
                xp[i]  = yn[i];
            }
        }
    }
}

// out = gelu_exact(zT) @ w_proj + b_proj ; mask = 0
__global__ void ncde_proj(const float* __restrict__ zT,
                          const float* __restrict__ w_proj, const float* __restrict__ b_proj,
                          float* __restrict__ out, float* __restrict__ mask)
{
    __shared__ float gz[16][64];
    const int blk = blockIdx.x;
    const int tid = threadIdx.x;
    const int r16 = tid >> 4, f = tid & 15;
    const int row0 = blk * 16;

    #pragma unroll
    for (int i = 0; i < 4; ++i) {
        int idx = tid + i * 256;
        int r = idx >> 6, k = idx & 63;
        float zv = zT[(size_t)(row0 + r) * HH + k];
        gz[r][k] = 0.5f * zv * (1.0f + erff(zv * 0.70710678118654752f));
    }
    __syncthreads();

    float acc = b_proj[f];
    #pragma unroll
    for (int k = 0; k < 64; ++k)
        acc = fmaf(gz[r16][k], w_proj[k * FF + f], acc);
    out[(size_t)(row0 + r16) * FF + f] = acc;
    if (f == 0) mask[row0 + r16] = 0.0f;
}

extern "C" void kernel_launch(void* const* d_in, const int* in_sizes, int n_in,
                              void* d_out, int out_size, void* d_ws, size_t ws_size,
                              hipStream_t stream)
{
    (void)in_sizes; (void)n_in; (void)d_ws; (void)ws_size; (void)out_size;
    const float* x      = (const float*)d_in[0];
    const float* wi1    = (const float*)d_in[1];
    const float* bi1    = (const float*)d_in[2];
    const float* wi2    = (const float*)d_in[3];
    const float* bi2    = (const float*)d_in[4];
    const float* w_in   = (const float*)d_in[5];
    const float* b_in   = (const float*)d_in[6];
    const float* w_hid  = (const float*)d_in[7];
    const float* b_hid  = (const float*)d_in[8];
    const float* w_out  = (const float*)d_in[9];
    const float* b_out  = (const float*)d_in[10];
    const float* w_proj = (const float*)d_in[11];
    const float* b_proj = (const float*)d_in[12];

    float* zT   = (float*)d_out;                       // B*T*H
    float* outp = zT + (size_t)BB * TT * HH;           // B*T*F
    float* mask = outp + (size_t)BB * TT * FF;         // B*T

    ncde_main<<<dim3(BB), dim3(512), 0, stream>>>(
        x, wi1, bi1, wi2, bi2, w_in, b_in, w_hid, b_hid, w_out, b_out, zT);
    ncde_proj<<<dim3((BB * TT) / 16), dim3(256), 0, stream>>>(
        zT, w_proj, b_proj, outp, mask);
}

// Round 23
// 11717.330 us; speedup vs baseline: 1.0772x; 1.0772x over previous
//
#include <hip/hip_runtime.h>
#include <math.h>

#define BB 32
#define TT 2048
#define FF 16
#define CC 17
#define HH 64

typedef float v2f __attribute__((ext_vector_type(2)));
typedef float v4f __attribute__((ext_vector_type(4)));
typedef unsigned v4u __attribute__((ext_vector_type(4)));
typedef _Float16 h2 __attribute__((ext_vector_type(2)));

__device__ __forceinline__ float rl(float v, int lane) {
    return __int_as_float(__builtin_amdgcn_readlane(__float_as_int(v), lane));
}
__device__ __forceinline__ unsigned rlu(unsigned v, int lane) {
    return (unsigned)__builtin_amdgcn_readlane((int)v, lane);
}
__device__ __forceinline__ float uf(float v) {
    return __int_as_float(__builtin_amdgcn_readfirstlane(__float_as_int(v)));
}
__device__ __forceinline__ float ftanh(float x) {
    float e = __builtin_amdgcn_exp2f(x * 2.88539008177792681472f); // exp(2x)
    return 1.0f - 2.0f * __builtin_amdgcn_rcpf(e + 1.0f);
}
__device__ __forceinline__ float fdot2u(unsigned a, unsigned b, float c) {
    return __builtin_amdgcn_fdot2(__builtin_bit_cast(h2, a),
                                  __builtin_bit_cast(h2, b), c, false);
}
// pack (a,b) to f16x2, scaled by 2^8 (weights); RN; init-time only
__device__ __forceinline__ unsigned packw(float a, float b) {
    h2 p; p.x = (_Float16)(a * 256.0f); p.y = (_Float16)(b * 256.0f);
    return __builtin_bit_cast(unsigned, p);
}
// LDS-only barrier: no vmcnt(0) drain.
__device__ __forceinline__ void bar_lds() {
    asm volatile("s_waitcnt lgkmcnt(0)\n\ts_barrier" ::: "memory");
}
#define PIN(v) asm volatile("" : "+v"(v))

// FINAL (== R21, measured 11.73 ms; R20 twin at 11.72 with 2.4x the bank
// conflicts). Role-split pipeline, 3 barriers/G:
//  wave 0: hidden layers 0,1 fully in-register (layer0 from packb(z), layer1
//          chained via v_readlane broadcast; 32 packed-f16 weight regs each)
//  wave 1: hidden layers 2,3 (layer2 reads h2 from LDS -- the one necessary
//          cross-wave input -- layer3 readlane-chained)        -> barrier A
//  waves 2-7: out layer, {3,3,3,3,3,2} columns, h4 via uniform-address b128
//          broadcasts                                           -> barrier B/C
//  pg combine: permuted-slot write ((w-2+(l>>3))%6, bijective per row).
// Closed-out design space (measured): 5->3 sync rounds -7% (R14->R20);
// 3->2 rounds +8% (R22: single-wave serial chain + AGPR reads exceed the
// saved barrier); more waves/fused elements spill (R5/R10/R15/R16/R18);
// 1 wave/SIMD exposes stalls (R13/R17); atomics serialize (R11); issue/LDS/
// hazard micro-opts each <=2% (R9/R12/R14/R21). Latency-bound: 8188 serial
// G-calls x (4 serial MLP layers + 2 handoffs), parallelism = 32 blocks.
__attribute__((amdgpu_waves_per_eu(2, 2)))
__launch_bounds__(512)
__global__ void ncde_main(const float* __restrict__ x,
                          const float* __restrict__ wi1, const float* __restrict__ bi1,
                          const float* __restrict__ wi2, const float* __restrict__ bi2,
                          const float* __restrict__ w_in, const float* __restrict__ b_in,
                          const float* __restrict__ w_hid, const float* __restrict__ b_hid,
                          const float* __restrict__ w_out, const float* __restrict__ b_out,
                          float* __restrict__ zT)
{
    const int b   = blockIdx.x;
    const int tid = threadIdx.x;
    const int w   = tid >> 6;
    const int l   = tid & 63;

    __shared__ __align__(16) unsigned h2b[32];   // h2 (w0 -> w1)
    __shared__ __align__(16) unsigned hbuf[32];  // h4 (w1 -> out waves)
    __shared__ float pgqt[64][20];               // [h-row][6 pg cols + pad]

    // role parameters (wave-uniform)
    const int nc    = (w >= 2) ? ((w < 7) ? 3 : 2) : 0;   // out columns owned
    const int cbase = (w < 7) ? 3 * (w - 2) : 15;         // first column (w>=2)
    const int pcol  = (w >= 2) ? ((w - 2 + (l >> 3)) % 6) : 0;  // permuted pg slot

    // ---- weights: 96 u32, role-dependent content ----
    unsigned wreg[96];
    #pragma unroll
    for (int i = 0; i < 96; ++i) wreg[i] = 0u;
    float bA = 0.f, bB = 0.f, bC = 0.f;
    if (w == 0) {
        #pragma unroll
        for (int p = 0; p < 32; ++p) {
            wreg[p]      = packw(w_in[(2 * p) * HH + l],          w_in[(2 * p + 1) * HH + l]);
            wreg[32 + p] = packw(w_hid[(0 * HH + 2 * p) * HH + l], w_hid[(0 * HH + 2 * p + 1) * HH + l]);
        }
        bA = b_in[l];  bB = b_hid[l];
    } else if (w == 1) {
        #pragma unroll
        for (int p = 0; p < 32; ++p) {
            wreg[p]      = packw(w_hid[(1 * HH + 2 * p) * HH + l], w_hid[(1 * HH + 2 * p + 1) * HH + l]);
            wreg[32 + p] = packw(w_hid[(2 * HH + 2 * p) * HH + l], w_hid[(2 * HH + 2 * p + 1) * HH + l]);
        }
        bA = b_hid[HH + l];  bB = b_hid[2 * HH + l];
    } else {
        #pragma unroll
        for (int i = 0; i < 3; ++i) {
            if (i < nc) {
                int c = cbase + i;
                #pragma unroll
                for (int p = 0; p < 32; ++p)
                    wreg[32 * i + p] = packw(w_out[(2 * p) * (CC * HH) + l * CC + c],
                                             w_out[(2 * p + 1) * (CC * HH) + l * CC + c]);
            }
        }
        bA = b_out[l * CC + cbase];
        bB = b_out[l * CC + cbase + 1];
        if (nc == 3) bC = b_out[l * CC + cbase + 2];
    }
    #pragma unroll
    for (int i = 0; i < 96; ++i) PIN(wreg[i]);
    PIN(bA); PIN(bB); PIN(bC);

    // ---- z0 = relu(xa0 @ wi1 + bi1) @ wi2 + bi2 (f32, once, all waves) ----
    float z;
    {
        float h0 = bi1[l];
        #pragma unroll
        for (int c = 1; c < CC; ++c)
            h0 = fmaf(x[(size_t)b * TT * FF + (c - 1)], wi1[c * HH + l], h0);
        h0 = fmaxf(h0, 0.0f);
        z = bi2[l];
        #pragma unroll
        for (int k = 0; k < 64; ++k)
            z = fmaf(rl(h0, k), wi2[k * HH + l], z);
    }
    if (w == 7) zT[(size_t)b * TT * HH + l] = z;

    // pack v*2^-8 into f16x2; every lane ends holding pair (v[2j],v[2j+1]), j=l>>1
    auto packb = [&](float v) -> unsigned {
        float hs = v * 0.00390625f;
        float pr = __shfl_xor(hs, 1);
        float a  = (l & 1) ? pr : hs;
        float bb = (l & 1) ? hs : pr;
        return __builtin_bit_cast(unsigned, __builtin_amdgcn_cvt_pkrtz(a, bb));
    };

    // full 64-wide matvec column for lane l; h pairs broadcast via readlane
    auto LAYER_RL = [&](const unsigned* Wc, float bias, unsigned hp) -> float {
        float a0 = bias, a1 = 0.f, a2 = 0.f, a3 = 0.f;
        #pragma unroll
        for (int p = 0; p < 32; p += 4) {
            unsigned s0 = rlu(hp, 2 * p);
            unsigned s1 = rlu(hp, 2 * p + 2);
            unsigned s2 = rlu(hp, 2 * p + 4);
            unsigned s3 = rlu(hp, 2 * p + 6);
            a0 = fdot2u(s0, Wc[p],     a0);
            a1 = fdot2u(s1, Wc[p + 1], a1);
            a2 = fdot2u(s2, Wc[p + 2], a2);
            a3 = fdot2u(s3, Wc[p + 3], a3);
        }
        return fmaxf((a0 + a1) + (a2 + a3), 0.0f);
    };
    // same but h pairs from LDS uniform-address b128 (cross-wave input)
    auto LAYER_LDS = [&](const unsigned* Wc, float bias, const unsigned* hs) -> float {
        v4u q0 = *reinterpret_cast<const v4u*>(&hs[0]);
        v4u q1 = *reinterpret_cast<const v4u*>(&hs[4]);
        v4u q2 = *reinterpret_cast<const v4u*>(&hs[8]);
        v4u q3 = *reinterpret_cast<const v4u*>(&hs[12]);
        v4u q4 = *reinterpret_cast<const v4u*>(&hs[16]);
        v4u q5 = *reinterpret_cast<const v4u*>(&hs[20]);
        v4u q6 = *reinterpret_cast<const v4u*>(&hs[24]);
        v4u q7 = *reinterpret_cast<const v4u*>(&hs[28]);
        float a0 = bias, a1 = 0.f, a2 = 0.f, a3 = 0.f;
        a0 = fdot2u(q0.x, Wc[0],  a0); a1 = fdot2u(q0.y, Wc[1],  a1);
        a2 = fdot2u(q0.z, Wc[2],  a2); a3 = fdot2u(q0.w, Wc[3],  a3);
        a0 = fdot2u(q1.x, Wc[4],  a0); a1 = fdot2u(q1.y, Wc[5],  a1);
        a2 = fdot2u(q1.z, Wc[6],  a2); a3 = fdot2u(q1.w, Wc[7],  a3);
        a0 = fdot2u(q2.x, Wc[8],  a0); a1 = fdot2u(q2.y, Wc[9],  a1);
        a2 = fdot2u(q2.z, Wc[10], a2); a3 = fdot2u(q2.w, Wc[11], a3);
        a0 = fdot2u(q3.x, Wc[12], a0); a1 = fdot2u(q3.y, Wc[13], a1);
        a2 = fdot2u(q3.z, Wc[14], a2); a3 = fdot2u(q3.w, Wc[15], a3);
        a0 = fdot2u(q4.x, Wc[16], a0); a1 = fdot2u(q4.y, Wc[17], a1);
        a2 = fdot2u(q4.z, Wc[18], a2); a3 = fdot2u(q4.w, Wc[19], a3);
        a0 = fdot2u(q5.x, Wc[20], a0); a1 = fdot2u(q5.y, Wc[21], a1);
        a2 = fdot2u(q5.z, Wc[22], a2); a3 = fdot2u(q5.w, Wc[23], a3);
        a0 = fdot2u(q6.x, Wc[24], a0); a1 = fdot2u(q6.y, Wc[25], a1);
        a2 = fdot2u(q6.z, Wc[26], a2); a3 = fdot2u(q6.w, Wc[27], a3);
        a0 = fdot2u(q7.x, Wc[28], a0); a1 = fdot2u(q7.y, Wc[29], a1);
        a2 = fdot2u(q7.z, Wc[30], a2); a3 = fdot2u(q7.w, Wc[31], a3);
        return fmaxf((a0 + a1) + (a2 + a3), 0.0f);
    };
    // out-layer dot from preloaded q regs (no relu)
    auto DOT32 = [&](const unsigned* Wc, float bias,
                     v4u q0, v4u q1, v4u q2, v4u q3,
                     v4u q4, v4u q5, v4u q6, v4u q7) -> float {
        float a0 = bias, a1 = 0.f, a2 = 0.f, a3 = 0.f;
        a0 = fdot2u(q0.x, Wc[0],  a0); a1 = fdot2u(q0.y, Wc[1],  a1);
        a2 = fdot2u(q0.z, Wc[2],  a2); a3 = fdot2u(q0.w, Wc[3],  a3);
        a0 = fdot2u(q1.x, Wc[4],  a0); a1 = fdot2u(q1.y, Wc[5],  a1);
        a2 = fdot2u(q1.z, Wc[6],  a2); a3 = fdot2u(q1.w, Wc[7],  a3);
        a0 = fdot2u(q2.x, Wc[8],  a0); a1 = fdot2u(q2.y, Wc[9],  a1);
        a2 = fdot2u(q2.z, Wc[10], a2); a3 = fdot2u(q2.w, Wc[11], a3);
        a0 = fdot2u(q3.x, Wc[12], a0); a1 = fdot2u(q3.y, Wc[13], a1);
        a2 = fdot2u(q3.z, Wc[14], a2); a3 = fdot2u(q3.w, Wc[15], a3);
        a0 = fdot2u(q4.x, Wc[16], a0); a1 = fdot2u(q4.y, Wc[17], a1);
        a2 = fdot2u(q4.z, Wc[18], a2); a3 = fdot2u(q4.w, Wc[19], a3);
        a0 = fdot2u(q5.x, Wc[20], a0); a1 = fdot2u(q5.y, Wc[21], a1);
        a2 = fdot2u(q5.z, Wc[22], a2); a3 = fdot2u(q5.w, Wc[23], a3);
        a0 = fdot2u(q6.x, Wc[24], a0); a1 = fdot2u(q6.y, Wc[25], a1);
        a2 = fdot2u(q6.z, Wc[26], a2); a3 = fdot2u(q6.w, Wc[27], a3);
        a0 = fdot2u(q7.x, Wc[28], a0); a1 = fdot2u(q7.y, Wc[29], a1);
        a2 = fdot2u(q7.z, Wc[30], a2); a3 = fdot2u(q7.w, Wc[31], a3);
        return (a0 + a1) + (a2 + a3);
    };

    // ---- g(zin, xd[3]) : 3-barrier pipeline, readlane-chained hidden ----
    auto G = [&](float zin, float xd0, float xd1, float xd2) -> float {
        if (w == 0) {
            unsigned hp0 = packb(zin);
            float h1v = LAYER_RL(&wreg[0],  bA, hp0);   // layer 0 (pure registers)
            unsigned hp1 = packb(h1v);
            float h2v = LAYER_RL(&wreg[32], bB, hp1);   // layer 1
            unsigned hp2 = packb(h2v);
            if (!(l & 1)) h2b[l >> 1] = hp2;
        }
        bar_lds();   // A: h2 published
        if (w == 1) {
            float h3v = LAYER_LDS(&wreg[0], bA, h2b);   // layer 2 (cross-wave input)
            unsigned hp3 = packb(h3v);
            float h4v = LAYER_RL(&wreg[32], bB, hp3);   // layer 3 (pure registers)
            unsigned hp4 = packb(h4v);
            if (!(l & 1)) hbuf[l >> 1] = hp4;
        }
        bar_lds();   // B: h4 published
        if (w >= 2) {
            v4u q0 = *reinterpret_cast<const v4u*>(&hbuf[0]);
            v4u q1 = *reinterpret_cast<const v4u*>(&hbuf[4]);
            v4u q2 = *reinterpret_cast<const v4u*>(&hbuf[8]);
            v4u q3 = *reinterpret_cast<const v4u*>(&hbuf[12]);
            v4u q4 = *reinterpret_cast<const v4u*>(&hbuf[16]);
            v4u q5 = *reinterpret_cast<const v4u*>(&hbuf[20]);
            v4u q6 = *reinterpret_cast<const v4u*>(&hbuf[24]);
            v4u q7 = *reinterpret_cast<const v4u*>(&hbuf[28]);
            float u0 = DOT32(&wreg[0],  bA, q0, q1, q2, q3, q4, q5, q6, q7);
            float u1 = DOT32(&wreg[32], bB, q0, q1, q2, q3, q4, q5, q6, q7);
            float pg = ftanh(u0) * xd0 + ftanh(u1) * xd1;
            if (nc == 3) {
                float u2 = DOT32(&wreg[64], bC, q0, q1, q2, q3, q4, q5, q6, q7);
                pg = fmaf(ftanh(u2), xd2, pg);
            }
            pgqt[l][pcol] = pg;    // permuted slot: bijective per row, conflict-light
        }
        bar_lds();   // C: pg partials published
        const float* pr = &pgqt[l][0];
        v4f r0 = *reinterpret_cast<const v4f*>(pr);
        v2f r1 = *reinterpret_cast<const v2f*>(pr + 4);
        return ((r0.x + r0.y) + (r0.z + r0.w)) + (r1.x + r1.y);
    };

    // ---- time scan: wave w carries xd for its out columns (nc of them) ----
    const float* xb = x + (size_t)b * TT * FF;
    float xp[3] = {0, 0, 0}, dcv[3] = {0, 0, 0}, dpv[3] = {0, 0, 0};
    #pragma unroll
    for (int i = 0; i < 3; ++i) {
        if (i < nc) {
            int f = cbase + i - 1;              // feature; f<0 => time channel
            float v0 = (f < 0) ? 0.f : uf(xb[f]);
            float v1 = (f < 0) ? 0.f : uf(xb[FF + f]);
            dcv[i] = (f < 0) ? 1.0f : (v1 - v0);
            dpv[i] = dcv[i];
            xp[i]  = v1;
        }
    }

    #pragma unroll 1
    for (int t = 0; t < TT - 1; ++t) {
        const float f43 = 4.0f / 3.0f;
        float x2[3] = {0, 0, 0};
        #pragma unroll
        for (int i = 0; i < 3; ++i)
            if (i < nc) x2[i] = dpv[i] + f43 * (dcv[i] - dpv[i]);

        int tn = (t + 2 < TT) ? (t + 2) : (TT - 1);
        float yn[3] = {0, 0, 0};
        #pragma unroll
        for (int i = 0; i < 3; ++i) {
            if (i < nc) {
                int f = cbase + i - 1;
                yn[i] = (f < 0) ? 0.f : uf(xb[tn * FF + f]);
            }
        }

        float k1 = G(z, dpv[0], dpv[1], dpv[2]);
        float k2 = G(z + k1 * (1.0f / 3.0f), dcv[0], dcv[1], dcv[2]);
        float k3 = G(z + (k2 - k1 * (1.0f / 3.0f)), x2[0], x2[1], x2[2]);
        float k4 = G(z + (k1 - k2 + k3), dcv[0], dcv[1], dcv[2]);
        z = z + 0.125f * (k1 + 3.0f * (k2 + k3) + k4);

        if (w == 7) zT[((size_t)b * TT + t + 1) * HH + l] = z;

        #pragma unroll
        for (int i = 0; i < 3; ++i) {
            if (i < nc) {
                int f = cbase + i - 1;
                dpv[i] = dcv[i];
                dcv[i] = (f < 0) ? 1.0f : (yn[i] - xp[i]);
                xp[i]  = yn[i];
            }
        }
    }
}

// out = gelu_exact(zT) @ w_proj + b_proj ; mask = 0
__global__ void ncde_proj(const float* __restrict__ zT,
                          const float* __restrict__ w_proj, const float* __restrict__ b_proj,
                          float* __restrict__ out, float* __restrict__ mask)
{
    __shared__ float gz[16][64];
    const int blk = blockIdx.x;
    const int tid = threadIdx.x;
    const int r16 = tid >> 4, f = tid & 15;
    const int row0 = blk * 16;

    #pragma unroll
    for (int i = 0; i < 4; ++i) {
        int idx = tid + i * 256;
        int r = idx >> 6, k = idx & 63;
        float zv = zT[(size_t)(row0 + r) * HH + k];
        gz[r][k] = 0.5f * zv * (1.0f + erff(zv * 0.70710678118654752f));
    }
    __syncthreads();

    float acc = b_proj[f];
    #pragma unroll
    for (int k = 0; k < 64; ++k)
        acc = fmaf(gz[r16][k], w_proj[k * FF + f], acc);
    out[(size_t)(row0 + r16) * FF + f] = acc;
    if (f == 0) mask[row0 + r16] = 0.0f;
}

extern "C" void kernel_launch(void* const* d_in, const int* in_sizes, int n_in,
                              void* d_out, int out_size, void* d_ws, size_t ws_size,
                              hipStream_t stream)
{
    (void)in_sizes; (void)n_in; (void)d_ws; (void)ws_size; (void)out_size;
    const float* x      = (const float*)d_in[0];
    const float* wi1    = (const float*)d_in[1];
    const float* bi1    = (const float*)d_in[2];
    const float* wi2    = (const float*)d_in[3];
    const float* bi2    = (const float*)d_in[4];
    const float* w_in   = (const float*)d_in[5];
    const float* b_in   = (const float*)d_in[6];
    const float* w_hid  = (const float*)d_in[7];
    const float* b_hid  = (const float*)d_in[8];
    const float* w_out  = (const float*)d_in[9];
    const float* b_out  = (const float*)d_in[10];
    const float* w_proj = (const float*)d_in[11];
    const float* b_proj = (const float*)d_in[12];

    float* zT   = (float*)d_out;                       // B*T*H
    float* outp = zT + (size_t)BB * TT * HH;           // B*T*F
    float* mask = outp + (size_t)BB * TT * FF;         // B*T

    ncde_main<<<dim3(BB), dim3(512), 0, stream>>>(
        x, wi1, bi1, wi2, bi2, w_in, b_in, w_hid, b_hid, w_out, b_out, zT);
    ncde_proj<<<dim3((BB * TT) / 16), dim3(256), 0, stream>>>(
        zT, w_proj, b_proj, outp, mask);
}